// Round 18
// baseline (296.643 us; speedup 1.0000x reference)
//
#include <hip/hip_runtime.h>
#include <hip/hip_bf16.h>
#include <math.h>

#define NH 16
#define S_LEN 1024
#define DK 64
#define D_MODEL 1024
#define HSZ 8388608          // B*NH*S*DK elements per q/k/v buffer

typedef __attribute__((ext_vector_type(8))) short bf16x8;
typedef __attribute__((ext_vector_type(4))) float f32x4;
typedef unsigned short USH;

#define EXPSCALE 0.1803368801111204f   // 0.125 * log2(e)

__device__ __forceinline__ float fast_exp2(float x) {
    return __builtin_amdgcn_exp2f(x);
}

__device__ __forceinline__ short f2b(float x) {
    union { __hip_bfloat16 h; short s; } u;
    u.h = __float2bfloat16(x);
    return u.s;
}
__device__ __forceinline__ float b2f(USH u) {
    union { unsigned i; float f; } x;
    x.i = (unsigned)u << 16;
    return x.f;
}

__device__ __forceinline__ void gload16(const void* src, void* lds) {
    __builtin_amdgcn_global_load_lds(
        (const __attribute__((address_space(1))) void*)src,
        (__attribute__((address_space(3))) void*)lds,
        16, 0, 0);
}

// ---------------------------------------------------------------------------
// Fused prep: fp32->bf16 conv of x  +  transpose-convert of W_attn, W_proj.
// ---------------------------------------------------------------------------
__global__ __launch_bounds__(256)
void prep_kernel(const float* __restrict__ x, USH* __restrict__ xb,
                 const float* __restrict__ W_attn, USH* __restrict__ watt,
                 const float* __restrict__ W_proj, USH* __restrict__ wproj) {
    const int blk = blockIdx.x;
    const int t = threadIdx.x;
    if (blk < 4096) {
        const int i = (blk * 256 + t) * 8;
        const float4 a = *(const float4*)&x[i];
        const float4 b = *(const float4*)&x[i + 4];
        ushort4 o0, o1;
        o0.x = (USH)f2b(a.x); o0.y = (USH)f2b(a.y); o0.z = (USH)f2b(a.z); o0.w = (USH)f2b(a.w);
        o1.x = (USH)f2b(b.x); o1.y = (USH)f2b(b.y); o1.z = (USH)f2b(b.z); o1.w = (USH)f2b(b.w);
        *(ushort4*)&xb[i] = o0;
        *(ushort4*)&xb[i + 4] = o1;
        return;
    }
    __shared__ USH Ts[64][65];
    const float* in;
    USH* out;
    int R, C, r0, c0;
    if (blk < 4864) {
        const int idx = blk - 4096;
        in = W_attn; out = watt; R = 1024; C = 3072;
        c0 = (idx % 48) * 64; r0 = (idx / 48) * 64;
    } else {
        const int idx = blk - 4864;
        in = W_proj; out = wproj; R = 1024; C = 1024;
        c0 = (idx % 16) * 64; r0 = (idx / 16) * 64;
    }
    const int tr = t >> 4;
    const int tc4 = (t & 15) * 4;
    #pragma unroll
    for (int ph = 0; ph < 4; ++ph) {
        const int r = ph * 16 + tr;
        const float4 v = *(const float4*)&in[(size_t)(r0 + r) * C + c0 + tc4];
        Ts[tc4 + 0][r] = (USH)f2b(v.x);
        Ts[tc4 + 1][r] = (USH)f2b(v.y);
        Ts[tc4 + 2][r] = (USH)f2b(v.z);
        Ts[tc4 + 3][r] = (USH)f2b(v.w);
    }
    __syncthreads();
    #pragma unroll
    for (int ph = 0; ph < 4; ++ph) {
        const int cc = ph * 16 + tr;
        ushort4 o;
        o.x = Ts[cc][tc4 + 0]; o.y = Ts[cc][tc4 + 1];
        o.z = Ts[cc][tc4 + 2]; o.w = Ts[cc][tc4 + 3];
        *(ushort4*)&out[(size_t)(c0 + cc) * R + r0 + tc4] = o;
    }
}

// ---------------------------------------------------------------------------
// 256x128-tile GEMM, BK=32, 512 thr (8 waves 4Mx2N), tri-buffered counted-
// vmcnt pipeline. QKV=1: V n-tiles written transposed via in-LDS transpose.
// ---------------------------------------------------------------------------
template<int QKV>
__global__ __launch_bounds__(512)
void gemm256_kernel(const USH* __restrict__ A, const USH* __restrict__ Bt,
                    const float* __restrict__ bias,
                    float* __restrict__ Cf, USH* __restrict__ Cq,
                    USH* __restrict__ Ck, USH* __restrict__ Cvt,
                    int N, int NTILN) {
    __shared__ __align__(16) USH lds[36864];   // 72 KB
    const int t = threadIdx.x;
    const int w = t >> 6, lane = t & 63, g = lane >> 4, c = lane & 15;
    const int wm = w >> 1, wn = w & 1;         // 4M x 2N waves
    const int nwg = NTILN * 32;
    const int bid = blockIdx.x;
    const int swz = (bid & 7) * (nwg >> 3) + (bid >> 3);   // nwg%8==0 bijective
    const int bn0 = (swz % NTILN) * 128;
    const int bm0 = (swz / NTILN) * 256;

    auto stage = [&](int kt, int slot) {
        const int k0 = kt * 32;
        char* base = (char*)lds + slot * 24576;
        #pragma unroll
        for (int q = 0; q < 2; ++q) {
            const int o = t * 16 + q * 8192;
            const int row = o >> 6;
            const int sc = (((o >> 4) & 3) ^ (row & 3)) * 8;
            gload16(A + (size_t)(bm0 + row) * 1024 + k0 + sc, base + o);
        }
        const int o = t * 16;
        const int row = o >> 6;
        const int sc = (((o >> 4) & 3) ^ (row & 3)) * 8;
        gload16(Bt + (size_t)(bn0 + row) * 1024 + k0 + sc, base + 16384 + o);
    };

    unsigned aoff[4], boff[4];
    #pragma unroll
    for (int i = 0; i < 4; ++i) {
        const int row = wm * 64 + i * 16 + c;
        aoff[i] = (unsigned)(row * 64) + (((unsigned)(g ^ (row & 3))) << 4);
        const int rn = wn * 64 + i * 16 + c;
        boff[i] = 16384u + (unsigned)(rn * 64) + (((unsigned)(g ^ (rn & 3))) << 4);
    }

    f32x4 acc[4][4];
    #pragma unroll
    for (int i = 0; i < 4; ++i)
        #pragma unroll
        for (int j = 0; j < 4; ++j) acc[i][j] = (f32x4)0.f;

    stage(0, 0);
    stage(1, 1);

    int cur = 0;
    for (int kt = 0; kt < 32; ++kt) {
        if (kt < 31) asm volatile("s_waitcnt vmcnt(3)" ::: "memory");
        else         asm volatile("s_waitcnt vmcnt(0)" ::: "memory");
        __builtin_amdgcn_s_barrier();

        const int slot2 = (cur + 2 >= 3) ? cur - 1 : cur + 2;
        if (kt + 2 < 32)
            stage(kt + 2, slot2);

        const char* sb = (const char*)lds + cur * 24576;
        bf16x8 af[4], bfr[4];
        #pragma unroll
        for (int i = 0; i < 4; ++i) af[i] = *(const bf16x8*)(sb + aoff[i]);
        #pragma unroll
        for (int j = 0; j < 4; ++j) bfr[j] = *(const bf16x8*)(sb + boff[j]);

        __builtin_amdgcn_s_setprio(1);
        #pragma unroll
        for (int i = 0; i < 4; ++i)
            #pragma unroll
            for (int j = 0; j < 4; ++j)
                acc[i][j] = __builtin_amdgcn_mfma_f32_16x16x32_bf16(
                    af[i], bfr[j], acc[i][j], 0, 0, 0);
        __builtin_amdgcn_s_setprio(0);

        cur = (cur + 1 == 3) ? 0 : cur + 1;
    }

    if (QKV) {
        if (bn0 < 2048) {
            #pragma unroll
            for (int i = 0; i < 4; ++i) {
                #pragma unroll
                for (int reg = 0; reg < 4; ++reg) {
                    const int m = bm0 + wm * 64 + i * 16 + g * 4 + reg;
                    const int b = m >> 10, s = m & 1023;
                    #pragma unroll
                    for (int j = 0; j < 4; ++j) {
                        const int n = bn0 + wn * 64 + j * 16 + c;
                        const float v = acc[i][j][reg] + bias[n];
                        const int which = n >> 10;
                        const int h = (n & 1023) >> 6, d = n & 63;
                        const size_t idx = (((size_t)(b * NH + h)) * S_LEN + s) * DK + d;
                        if (which == 0) Cq[idx] = (USH)f2b(v);
                        else            Ck[idx] = (USH)f2b(v);
                    }
                }
            }
        } else {
            __syncthreads();
            #pragma unroll
            for (int i = 0; i < 4; ++i) {
                const int m_local = wm * 64 + i * 16 + g * 4;
                #pragma unroll
                for (int j = 0; j < 4; ++j) {
                    const int n_local = wn * 64 + j * 16 + c;
                    const int n = bn0 + n_local;
                    ushort4 pk;
                    pk.x = (USH)f2b(acc[i][j][0] + bias[n]);
                    pk.y = (USH)f2b(acc[i][j][1] + bias[n]);
                    pk.z = (USH)f2b(acc[i][j][2] + bias[n]);
                    pk.w = (USH)f2b(acc[i][j][3] + bias[n]);
                    unsigned byte = ((unsigned)(n_local * 512 + m_local * 2))
                                  ^ (((unsigned)n_local & 7) << 4);
                    *(ushort4*)((char*)lds + byte) = pk;
                }
            }
            __syncthreads();
            const int b = bm0 >> 10, s0 = bm0 & 1023;
            const int h0 = (bn0 & 1023) >> 6;
            #pragma unroll
            for (int e = 0; e < 8; ++e) {
                const int task = e * 512 + t;
                const int n_local = task >> 5;
                const int chunk = task & 31;
                unsigned byte = ((unsigned)(n_local * 512 + chunk * 16))
                              ^ (((unsigned)n_local & 7) << 4);
                bf16x8 v = *(const bf16x8*)((char*)lds + byte);
                const int h = h0 + (n_local >> 6);
                const int d = n_local & 63;
                *(bf16x8*)&Cvt[(((size_t)(b * NH + h)) * DK + d) * S_LEN
                               + s0 + chunk * 8] = v;
            }
        }
    } else {
        #pragma unroll
        for (int i = 0; i < 4; ++i) {
            #pragma unroll
            for (int reg = 0; reg < 4; ++reg) {
                const int m = bm0 + wm * 64 + i * 16 + g * 4 + reg;
                #pragma unroll
                for (int j = 0; j < 4; ++j) {
                    const int n = bn0 + wn * 64 + j * 16 + c;
                    Cf[(size_t)m * N + n] = acc[i][j][reg] + bias[n];
                }
            }
        }
    }
}

// ---------------------------------------------------------------------------
// BARRIER-FREE flash attention: each wave owns 16 q-rows, fully independent.
// K/V/Q fragments read DIRECTLY from global (L2-served; K/V per head = 256KB,
// 16 heads/XCD = 4MB = per-XCD L2). All LDS is per-wave private (P roundtrip,
// qrel, taps, lsum) -> same-wave DS ordering, zero barriers after launch.
// Swapped QK^T (R17-verified): lane holds P[q = wrow0+c][k contiguous in r].
// Grid 2048 x 256 (4 indep waves/block); ~13KB LDS, ~52 VGPR -> high occ.
// ---------------------------------------------------------------------------
__global__ __launch_bounds__(256, 4)
void attn_mfma_kernel(const USH* __restrict__ qb,
                      const USH* __restrict__ kbuf,
                      const USH* __restrict__ vtg,
                      const float* __restrict__ lut_k,
                      const float* __restrict__ lut_v,
                      USH* __restrict__ ao) {
    const int bid = blockIdx.x;
    const int logical = (bid & 7) * 256 + (bid >> 3);   // XCD-contiguous
    const int bh = logical >> 4;                        // 16 blocks per bh
    const int quarter = 15 - (logical & 15);            // LPT: heavy first
    const int b = bh >> 4, h = bh & 15;
    const int t = threadIdx.x;
    const int w = t >> 6;          // 0..3
    const int lane = t & 63;
    const int g = lane >> 4;
    const int c = lane & 15;
    const int wrow0 = (quarter * 4 + w) * 16;   // wave's first q-row

    // per-wave private LDS: P 2048 + qrel 640 + taps 512 + lsum 64 = 3264 B
    __shared__ __align__(16) char smem[4 * 3264];
    char* pw     = smem + w * 3264;
    USH*  qrelw  = (USH*)(pw + 2048);            // [16][20] bf16
    USH*  tapsw  = (USH*)(pw + 2688);            // [16][16] bf16
    float* lsumw = (float*)(pw + 3200);          // [16]

    const USH* qp  = qb   + (size_t)bh * (S_LEN * DK);
    const USH* kp  = kbuf + (size_t)bh * (S_LEN * DK);
    const USH* vtp = vtg  + (size_t)bh * (S_LEN * DK);  // [d=64][s=1024]

    // ---- Q fragments direct from global (row = wrow0 + c) ----
    bf16x8 qa[2];
    #pragma unroll
    for (int kh = 0; kh < 2; ++kh)
        qa[kh] = *(const bf16x8*)&qp[(size_t)(wrow0 + c) * DK + kh * 32 + g * 8];

    // ---- qrel via MFMA, lut_k loaded direct (fp32 -> bf16) ----
    {
        f32x4 qr[2];
        qr[0] = (f32x4)0.f; qr[1] = (f32x4)0.f;
        #pragma unroll
        for (int sub2 = 0; sub2 < 2; ++sub2) {
            const int tap = sub2 * 16 + c;
            #pragma unroll
            for (int kh = 0; kh < 2; ++kh) {
                bf16x8 lb = (bf16x8)(short)0;
                if (tap < 17) {
                    const float* lr = &lut_k[tap * 64 + kh * 32 + g * 8];
                    const f32x4 lo = *(const f32x4*)lr;
                    const f32x4 hi = *(const f32x4*)(lr + 4);
                    lb[0] = f2b(lo[0]); lb[1] = f2b(lo[1]);
                    lb[2] = f2b(lo[2]); lb[3] = f2b(lo[3]);
                    lb[4] = f2b(hi[0]); lb[5] = f2b(hi[1]);
                    lb[6] = f2b(hi[2]); lb[7] = f2b(hi[3]);
                }
                qr[sub2] = __builtin_amdgcn_mfma_f32_16x16x32_bf16(
                    qa[kh], lb, qr[sub2], 0, 0, 0);
            }
        }
        #pragma unroll
        for (int sub2 = 0; sub2 < 2; ++sub2) {
            const int tap = sub2 * 16 + c;
            if (tap < 17) {
                #pragma unroll
                for (int r = 0; r < 4; ++r)
                    qrelw[(g * 4 + r) * 20 + tap] = (USH)f2b(qr[sub2][r]);
            }
        }
    }
    const float qrel0s = b2f(qrelw[c * 20]) * EXPSCALE;   // same-wave DS order

    f32x4 acc[4];
    #pragma unroll
    for (int dt = 0; dt < 4; ++dt) acc[dt] = (f32x4)0.f;
    float l_r = 0.f;

    const int NTw = (wrow0 >> 6) + 1;
    for (int tile = 0; tile < NTw; ++tile) {
        const int j0 = tile << 6;

        // ---- swapped QK^T: K fragments direct from global ----
        float p[4][4];
        f32x4 s[4];
        #pragma unroll
        for (int sub = 0; sub < 4; ++sub) {
            s[sub] = (f32x4)0.f;
            #pragma unroll
            for (int kh = 0; kh < 2; ++kh) {
                const bf16x8 kb = *(const bf16x8*)
                    &kp[(size_t)(j0 + sub * 16 + c) * DK + kh * 32 + g * 8];
                s[sub] = __builtin_amdgcn_mfma_f32_16x16x32_bf16(
                    kb, qa[kh], s[sub], 0, 0, 0);
            }
        }

        if (j0 + 79 <= wrow0) {
            // interior: dj <= -16 for all lanes -> tap 0
            #pragma unroll
            for (int sub = 0; sub < 4; ++sub)
                #pragma unroll
                for (int r = 0; r < 4; ++r)
                    p[sub][r] = fast_exp2(s[sub][r] * EXPSCALE + qrel0s);
        } else {
            const int iq = wrow0 + c;
            #pragma unroll
            for (int sub = 0; sub < 4; ++sub) {
                const int jbase = j0 + sub * 16 + g * 4;
                #pragma unroll
                for (int r = 0; r < 4; ++r) {
                    const int dj = jbase + r - iq;
                    int t17 = dj + 16;
                    t17 = t17 < 0 ? 0 : (t17 > 16 ? 16 : t17);
                    float pv = fast_exp2((s[sub][r] + b2f(qrelw[c * 20 + t17])) * EXPSCALE);
                    if (dj > 0) pv = 0.f;
                    p[sub][r] = pv;
                    if (dj >= -15 && dj <= 0)
                        tapsw[c * 16 + dj + 15] = (USH)f2b(pv);
                }
            }
        }

        #pragma unroll
        for (int sub = 0; sub < 4; ++sub)
            l_r += (p[sub][0] + p[sub][1]) + (p[sub][2] + p[sub][3]);

        // ---- P -> per-wave LDS: 4 x ds_write_b64 (row = c) ----
        #pragma unroll
        for (int sub = 0; sub < 4; ++sub) {
            const unsigned u0 = ((unsigned)(USH)f2b(p[sub][1]) << 16)
                              | (unsigned)(USH)f2b(p[sub][0]);
            const unsigned u1 = ((unsigned)(USH)f2b(p[sub][3]) << 16)
                              | (unsigned)(USH)f2b(p[sub][2]);
            uint2 val; val.x = u0; val.y = u1;
            unsigned byte = ((unsigned)(c * 128 + sub * 32 + g * 8))
                          ^ (((unsigned)c & 7) << 4);
            *(uint2*)(pw + byte) = val;
        }

        // ---- PV: P from LDS (A), V^T direct from global (B) ----
        bf16x8 pa[2];
        #pragma unroll
        for (int jh = 0; jh < 2; ++jh) {
            unsigned byte = ((unsigned)(c * 128 + jh * 64 + g * 16))
                          ^ (((unsigned)c & 7) << 4);
            pa[jh] = *(const bf16x8*)(pw + byte);
        }
        #pragma unroll
        for (int dt = 0; dt < 4; ++dt) {
            const int d = dt * 16 + c;
            #pragma unroll
            for (int jh = 0; jh < 2; ++jh) {
                const bf16x8 vb = *(const bf16x8*)
                    &vtp[(size_t)d * S_LEN + j0 + jh * 32 + g * 8];
                acc[dt] = __builtin_amdgcn_mfma_f32_16x16x32_bf16(
                    pa[jh], vb, acc[dt], 0, 0, 0);
            }
        }
    }

    // ---- row sums: lanes (c, c+16, c+32, c+48) hold row c partials ----
    float lsum = l_r;
    lsum += __shfl_xor(lsum, 16);
    lsum += __shfl_xor(lsum, 32);
    if (g == 0) lsumw[c] = lsum;

    // ---- epilogue: acc rows = g*4+r (wave-local), cols = dt*16+c ----
    #pragma unroll
    for (int r = 0; r < 4; ++r) {
        const int ilr = g * 4 + r;                 // wave-local q row
        const int iq = wrow0 + ilr;                // global q row
        const float lsr = lsumw[ilr];
        float c0 = lsr;
        float tp[16];
        #pragma unroll
        for (int tap = 0; tap < 16; ++tap) {
            const int jg = iq + tap - 15;
            const float pv = (jg >= 0) ? b2f(tapsw[ilr * 16 + tap]) : 0.f;
            tp[tap] = pv;
            c0 -= pv;
        }
        const float invl = 1.f / lsr;
        #pragma unroll
        for (int dt = 0; dt < 4; ++dt) {
            const int d = dt * 16 + c;
            float o = acc[dt][r] + c0 * lut_v[d];
            #pragma unroll
            for (int tap = 0; tap < 16; ++tap)
                o += tp[tap] * lut_v[(tap + 1) * 64 + d];
            o *= invl;
            ao[((size_t)b * S_LEN + iq) * D_MODEL + h * DK + d] = (USH)f2b(o);
        }
    }
}

// ---------------------------------------------------------------------------
extern "C" void kernel_launch(void* const* d_in, const int* in_sizes, int n_in,
                              void* d_out, int out_size, void* d_ws, size_t ws_size,
                              hipStream_t stream) {
    const float* x      = (const float*)d_in[0];
    const float* W_attn = (const float*)d_in[1];
    const float* b_attn = (const float*)d_in[2];
    const float* W_proj = (const float*)d_in[3];
    const float* b_proj = (const float*)d_in[4];
    const float* lut_k  = (const float*)d_in[5];
    const float* lut_v  = (const float*)d_in[6];
    float* out = (float*)d_out;

    // workspace layout (all USH)
    USH* qb    = (USH*)d_ws;            // 8M
    USH* kb    = qb + HSZ;              // 8M
    USH* vb    = kb + HSZ;              // 8M (unused)
    USH* vtg   = vb + HSZ;              // 8M (per-head transposed V, from GEMM)
    USH* aob   = vtg + HSZ;             // 8M
    USH* xb    = aob + HSZ;             // 8M
    USH* watt  = xb + HSZ;              // 3M
    USH* wproj = watt + 3145728;        // 1M

    // 0) fused prep: x->bf16, W_attn^T, W_proj^T
    prep_kernel<<<5120, 256, 0, stream>>>(x, xb, W_attn, watt, W_proj, wproj);

    // 1) QKV projection (256x128 tri-buffered, V written transposed in-kernel)
    gemm256_kernel<1><<<768, 512, 0, stream>>>(
        xb, watt, b_attn, nullptr, qb, kb, vtg, 3072, 24);

    // 2) attention (barrier-free independent waves, K/V direct from L2)
    attn_mfma_kernel<<<2048, 256, 0, stream>>>(qb, kb, vtg, lut_k, lut_v, aob);

    // 3) output projection (256x128 tri-buffered, fp32 out)
    gemm256_kernel<0><<<256, 512, 0, stream>>>(
        aob, wproj, b_proj, out, nullptr, nullptr, nullptr, 1024, 8);
}

// Round 19
// 193.973 us; speedup vs baseline: 1.5293x; 1.5293x over previous
//
#include <hip/hip_runtime.h>
#include <hip/hip_bf16.h>
#include <math.h>

#define NH 16
#define S_LEN 1024
#define DK 64
#define D_MODEL 1024
#define HSZ 8388608          // B*NH*S*DK elements per q/k/v buffer

typedef __attribute__((ext_vector_type(8))) short bf16x8;
typedef __attribute__((ext_vector_type(4))) float f32x4;
typedef unsigned short USH;

#define EXPSCALE 0.1803368801111204f   // 0.125 * log2(e)

__device__ __forceinline__ float fast_exp2(float x) {
    return __builtin_amdgcn_exp2f(x);
}

__device__ __forceinline__ short f2b(float x) {
    union { __hip_bfloat16 h; short s; } u;
    u.h = __float2bfloat16(x);
    return u.s;
}
__device__ __forceinline__ float b2f(USH u) {
    union { unsigned i; float f; } x;
    x.i = (unsigned)u << 16;
    return x.f;
}

__device__ __forceinline__ void gload16(const void* src, void* lds) {
    __builtin_amdgcn_global_load_lds(
        (const __attribute__((address_space(1))) void*)src,
        (__attribute__((address_space(3))) void*)lds,
        16, 0, 0);
}

// ---------------------------------------------------------------------------
// Fused prep: fp32->bf16 conv of x  +  transpose-convert of W_attn, W_proj.
// ---------------------------------------------------------------------------
__global__ __launch_bounds__(256)
void prep_kernel(const float* __restrict__ x, USH* __restrict__ xb,
                 const float* __restrict__ W_attn, USH* __restrict__ watt,
                 const float* __restrict__ W_proj, USH* __restrict__ wproj) {
    const int blk = blockIdx.x;
    const int t = threadIdx.x;
    if (blk < 4096) {
        const int i = (blk * 256 + t) * 8;
        const float4 a = *(const float4*)&x[i];
        const float4 b = *(const float4*)&x[i + 4];
        ushort4 o0, o1;
        o0.x = (USH)f2b(a.x); o0.y = (USH)f2b(a.y); o0.z = (USH)f2b(a.z); o0.w = (USH)f2b(a.w);
        o1.x = (USH)f2b(b.x); o1.y = (USH)f2b(b.y); o1.z = (USH)f2b(b.z); o1.w = (USH)f2b(b.w);
        *(ushort4*)&xb[i] = o0;
        *(ushort4*)&xb[i + 4] = o1;
        return;
    }
    __shared__ USH Ts[64][65];
    const float* in;
    USH* out;
    int R, C, r0, c0;
    if (blk < 4864) {
        const int idx = blk - 4096;
        in = W_attn; out = watt; R = 1024; C = 3072;
        c0 = (idx % 48) * 64; r0 = (idx / 48) * 64;
    } else {
        const int idx = blk - 4864;
        in = W_proj; out = wproj; R = 1024; C = 1024;
        c0 = (idx % 16) * 64; r0 = (idx / 16) * 64;
    }
    const int tr = t >> 4;
    const int tc4 = (t & 15) * 4;
    #pragma unroll
    for (int ph = 0; ph < 4; ++ph) {
        const int r = ph * 16 + tr;
        const float4 v = *(const float4*)&in[(size_t)(r0 + r) * C + c0 + tc4];
        Ts[tc4 + 0][r] = (USH)f2b(v.x);
        Ts[tc4 + 1][r] = (USH)f2b(v.y);
        Ts[tc4 + 2][r] = (USH)f2b(v.z);
        Ts[tc4 + 3][r] = (USH)f2b(v.w);
    }
    __syncthreads();
    #pragma unroll
    for (int ph = 0; ph < 4; ++ph) {
        const int cc = ph * 16 + tr;
        ushort4 o;
        o.x = Ts[cc][tc4 + 0]; o.y = Ts[cc][tc4 + 1];
        o.z = Ts[cc][tc4 + 2]; o.w = Ts[cc][tc4 + 3];
        *(ushort4*)&out[(size_t)(c0 + cc) * R + r0 + tc4] = o;
    }
}

// ---------------------------------------------------------------------------
// 256x128-tile GEMM, BK=32, 512 thr (8 waves 4Mx2N), tri-buffered counted-
// vmcnt pipeline. QKV=1: V n-tiles written transposed via in-LDS transpose.
// ---------------------------------------------------------------------------
template<int QKV>
__global__ __launch_bounds__(512)
void gemm256_kernel(const USH* __restrict__ A, const USH* __restrict__ Bt,
                    const float* __restrict__ bias,
                    float* __restrict__ Cf, USH* __restrict__ Cq,
                    USH* __restrict__ Ck, USH* __restrict__ Cvt,
                    int N, int NTILN) {
    __shared__ __align__(16) USH lds[36864];   // 72 KB
    const int t = threadIdx.x;
    const int w = t >> 6, lane = t & 63, g = lane >> 4, c = lane & 15;
    const int wm = w >> 1, wn = w & 1;         // 4M x 2N waves
    const int nwg = NTILN * 32;
    const int bid = blockIdx.x;
    const int swz = (bid & 7) * (nwg >> 3) + (bid >> 3);   // nwg%8==0 bijective
    const int bn0 = (swz % NTILN) * 128;
    const int bm0 = (swz / NTILN) * 256;

    auto stage = [&](int kt, int slot) {
        const int k0 = kt * 32;
        char* base = (char*)lds + slot * 24576;
        #pragma unroll
        for (int q = 0; q < 2; ++q) {
            const int o = t * 16 + q * 8192;
            const int row = o >> 6;
            const int sc = (((o >> 4) & 3) ^ (row & 3)) * 8;
            gload16(A + (size_t)(bm0 + row) * 1024 + k0 + sc, base + o);
        }
        const int o = t * 16;
        const int row = o >> 6;
        const int sc = (((o >> 4) & 3) ^ (row & 3)) * 8;
        gload16(Bt + (size_t)(bn0 + row) * 1024 + k0 + sc, base + 16384 + o);
    };

    unsigned aoff[4], boff[4];
    #pragma unroll
    for (int i = 0; i < 4; ++i) {
        const int row = wm * 64 + i * 16 + c;
        aoff[i] = (unsigned)(row * 64) + (((unsigned)(g ^ (row & 3))) << 4);
        const int rn = wn * 64 + i * 16 + c;
        boff[i] = 16384u + (unsigned)(rn * 64) + (((unsigned)(g ^ (rn & 3))) << 4);
    }

    f32x4 acc[4][4];
    #pragma unroll
    for (int i = 0; i < 4; ++i)
        #pragma unroll
        for (int j = 0; j < 4; ++j) acc[i][j] = (f32x4)0.f;

    stage(0, 0);
    stage(1, 1);

    int cur = 0;
    for (int kt = 0; kt < 32; ++kt) {
        if (kt < 31) asm volatile("s_waitcnt vmcnt(3)" ::: "memory");
        else         asm volatile("s_waitcnt vmcnt(0)" ::: "memory");
        __builtin_amdgcn_s_barrier();

        const int slot2 = (cur + 2 >= 3) ? cur - 1 : cur + 2;
        if (kt + 2 < 32)
            stage(kt + 2, slot2);

        const char* sb = (const char*)lds + cur * 24576;
        bf16x8 af[4], bfr[4];
        #pragma unroll
        for (int i = 0; i < 4; ++i) af[i] = *(const bf16x8*)(sb + aoff[i]);
        #pragma unroll
        for (int j = 0; j < 4; ++j) bfr[j] = *(const bf16x8*)(sb + boff[j]);

        __builtin_amdgcn_s_setprio(1);
        #pragma unroll
        for (int i = 0; i < 4; ++i)
            #pragma unroll
            for (int j = 0; j < 4; ++j)
                acc[i][j] = __builtin_amdgcn_mfma_f32_16x16x32_bf16(
                    af[i], bfr[j], acc[i][j], 0, 0, 0);
        __builtin_amdgcn_s_setprio(0);

        cur = (cur + 1 == 3) ? 0 : cur + 1;
    }

    if (QKV) {
        if (bn0 < 2048) {
            #pragma unroll
            for (int i = 0; i < 4; ++i) {
                #pragma unroll
                for (int reg = 0; reg < 4; ++reg) {
                    const int m = bm0 + wm * 64 + i * 16 + g * 4 + reg;
                    const int b = m >> 10, s = m & 1023;
                    #pragma unroll
                    for (int j = 0; j < 4; ++j) {
                        const int n = bn0 + wn * 64 + j * 16 + c;
                        const float v = acc[i][j][reg] + bias[n];
                        const int which = n >> 10;
                        const int h = (n & 1023) >> 6, d = n & 63;
                        const size_t idx = (((size_t)(b * NH + h)) * S_LEN + s) * DK + d;
                        if (which == 0) Cq[idx] = (USH)f2b(v);
                        else            Ck[idx] = (USH)f2b(v);
                    }
                }
            }
        } else {
            __syncthreads();
            #pragma unroll
            for (int i = 0; i < 4; ++i) {
                const int m_local = wm * 64 + i * 16 + g * 4;
                #pragma unroll
                for (int j = 0; j < 4; ++j) {
                    const int n_local = wn * 64 + j * 16 + c;
                    const int n = bn0 + n_local;
                    ushort4 pk;
                    pk.x = (USH)f2b(acc[i][j][0] + bias[n]);
                    pk.y = (USH)f2b(acc[i][j][1] + bias[n]);
                    pk.z = (USH)f2b(acc[i][j][2] + bias[n]);
                    pk.w = (USH)f2b(acc[i][j][3] + bias[n]);
                    unsigned byte = ((unsigned)(n_local * 512 + m_local * 2))
                                  ^ (((unsigned)n_local & 7) << 4);
                    *(ushort4*)((char*)lds + byte) = pk;
                }
            }
            __syncthreads();
            const int b = bm0 >> 10, s0 = bm0 & 1023;
            const int h0 = (bn0 & 1023) >> 6;
            #pragma unroll
            for (int e = 0; e < 8; ++e) {
                const int task = e * 512 + t;
                const int n_local = task >> 5;
                const int chunk = task & 31;
                unsigned byte = ((unsigned)(n_local * 512 + chunk * 16))
                              ^ (((unsigned)n_local & 7) << 4);
                bf16x8 v = *(const bf16x8*)((char*)lds + byte);
                const int h = h0 + (n_local >> 6);
                const int d = n_local & 63;
                *(bf16x8*)&Cvt[(((size_t)(b * NH + h)) * DK + d) * S_LEN
                               + s0 + chunk * 8] = v;
            }
        }
    } else {
        #pragma unroll
        for (int i = 0; i < 4; ++i) {
            #pragma unroll
            for (int reg = 0; reg < 4; ++reg) {
                const int m = bm0 + wm * 64 + i * 16 + g * 4 + reg;
                #pragma unroll
                for (int j = 0; j < 4; ++j) {
                    const int n = bn0 + wn * 64 + j * 16 + c;
                    Cf[(size_t)m * N + n] = acc[i][j][reg] + bias[n];
                }
            }
        }
    }
}

// ---------------------------------------------------------------------------
// MFMA flash attention: 4 waves x 32 q-rows (128/block), KVBLK=64, swapped
// QK^T (R17-verified), tri-buffered counted-vmcnt staging. Each K/V LDS
// fragment read is now shared by 2 q-halves -> DS reads per MFMA ~halved.
// LDS map (77440 B -> 2 blocks/CU):
//   0      ktb tri 3x8K      24576  vtb tri 3x8K
//   49152  pb 4 waves x 4KB [32 rows][64k] bf16, swz ^(row&7)<<4
//          (phase0 alias: qsb [128][64] swz, exactly 16KB)
//   65536  qrelb bf16 [128][20]   5120    (lutkb phase0-aliases ktb slot1)
//   70656  lvfb  bf16 [17][64]    2176
//   72832  tapssb bf16 [128][16]  4096
//   76928  lsumb f32 [128]        512
// ---------------------------------------------------------------------------
__global__ __launch_bounds__(256, 8)
void attn_mfma_kernel(const USH* __restrict__ qb,
                      const USH* __restrict__ kbuf,
                      const USH* __restrict__ vtg,
                      const float* __restrict__ lut_k,
                      const float* __restrict__ lut_v,
                      USH* __restrict__ ao) {
    const int bid = blockIdx.x;
    const int logical = (bid & 7) * 128 + (bid >> 3);   // XCD-contiguous bh
    const int ib = 7 - (logical & 7);                   // LPT: big ib first
    const int bh = logical >> 3;
    const int b = bh >> 4, h = bh & 15;
    const int i0 = ib * 128;
    const int t = threadIdx.x;
    const int w = t >> 6;          // 0..3
    const int lane = t & 63;
    const int g = lane >> 4;
    const int c = lane & 15;

    __shared__ __align__(16) char smem[77440];
    char* pb     = smem + 49152;             // P buffers (main loop)
    char* qsb    = smem + 49152;             // phase0 alias: q [128][64] swz
    char* lutkb  = smem + 8192;              // phase0 alias of ktb slot 1
    USH* qrelb   = (USH*)(smem + 65536);     // [128][20] bf16
    USH* lvfb    = (USH*)(smem + 70656);     // [17][64] bf16
    USH* tapssb  = (USH*)(smem + 72832);     // [128][16] bf16 p values
    float* lsumb = (float*)(smem + 76928);   // [128] row sums

    const USH* qp  = qb   + (size_t)bh * (S_LEN * DK);
    const USH* kp  = kbuf + (size_t)bh * (S_LEN * DK);
    const USH* vtp = vtg  + (size_t)bh * (S_LEN * DK);  // [d=64][s=1024]

    // stage one 64x64 K tile + V^T tile into slot (4 gload16 per thread)
    auto stage = [&](int j0, int slot) {
        #pragma unroll
        for (int q = 0; q < 2; ++q) {
            const int o = q * 4096 + t * 16;
            const int row = o >> 7;
            const int chunk = (o >> 4) & 7;
            const int sc = (chunk ^ (row & 7)) * 8;
            gload16(kp + (size_t)(j0 + row) * DK + sc, smem + slot * 8192 + o);
            gload16(vtp + (size_t)row * S_LEN + j0 + sc,
                    smem + 24576 + slot * 8192 + o);
        }
    };

    // ---- phase 0 ----
    stage(0, 0);
    for (int f = t; f < 2048; f += 256) {
        const int row = f >> 4, c4 = (f & 15) * 4;
        unsigned byte = ((unsigned)(row * 128 + c4 * 2)) ^ (((unsigned)row & 7) << 4);
        *(ushort4*)(qsb + byte) = *(const ushort4*)&qp[(size_t)(i0 + row) * DK + c4];
    }
    for (int e = t; e < 32 * 64; e += 256) {
        const int row = e >> 6, d = e & 63;
        const USH v = (row < 17) ? (USH)f2b(lut_k[row * 64 + d]) : (USH)0;
        unsigned byte = ((unsigned)(row * 128 + d * 2)) ^ (((unsigned)row & 7) << 4);
        *(USH*)(lutkb + byte) = v;
    }
    for (int e = t; e < 17 * 64; e += 256)
        lvfb[e] = (USH)f2b(lut_v[e]);
    __syncthreads();   // drains tile-0 gloads; qsb/lutkb/lvfb visible

    const int wrow0 = i0 + w * 32;   // wave's first q-row (32 rows/wave)

    // Q fragments: qa[qh][kh], local rows w*32 + qh*16 + c
    bf16x8 qa[2][2];
    #pragma unroll
    for (int qh = 0; qh < 2; ++qh) {
        const int row = w * 32 + qh * 16 + c;
        #pragma unroll
        for (int kh = 0; kh < 2; ++kh) {
            unsigned byte = ((unsigned)(row * 128 + kh * 64 + g * 16))
                          ^ (((unsigned)row & 7) << 4);
            qa[qh][kh] = *(const bf16x8*)(qsb + byte);
        }
    }

    // qrel via MFMA per q-half
    #pragma unroll
    for (int qh = 0; qh < 2; ++qh) {
        f32x4 qr[2];
        qr[0] = (f32x4)0.f; qr[1] = (f32x4)0.f;
        #pragma unroll
        for (int sub2 = 0; sub2 < 2; ++sub2) {
            const int tap = sub2 * 16 + c;
            #pragma unroll
            for (int kh = 0; kh < 2; ++kh) {
                unsigned byte = ((unsigned)(tap * 128 + kh * 64 + g * 16))
                              ^ (((unsigned)tap & 7) << 4);
                bf16x8 lb = *(const bf16x8*)(lutkb + byte);
                qr[sub2] = __builtin_amdgcn_mfma_f32_16x16x32_bf16(
                    qa[qh][kh], lb, qr[sub2], 0, 0, 0);
            }
        }
        #pragma unroll
        for (int sub2 = 0; sub2 < 2; ++sub2) {
            const int tap = sub2 * 16 + c;
            if (tap < 17) {
                #pragma unroll
                for (int r = 0; r < 4; ++r)
                    qrelb[(w * 32 + qh * 16 + g * 4 + r) * 20 + tap]
                        = (USH)f2b(qr[sub2][r]);
            }
        }
    }
    __syncthreads();   // qsb/lutkb reads done; pb/ktb1 writable; qrelb visible

    float qrel0s[2];
    #pragma unroll
    for (int qh = 0; qh < 2; ++qh)
        qrel0s[qh] = b2f(qrelb[(w * 32 + qh * 16 + c) * 20]) * EXPSCALE;

    const int NT = 2 * ib + 2;
    if (1 < NT) stage(64, 1);

    f32x4 acc[2][4];
    #pragma unroll
    for (int qh = 0; qh < 2; ++qh)
        #pragma unroll
        for (int dt = 0; dt < 4; ++dt) acc[qh][dt] = (f32x4)0.f;
    float l_r[2] = {0.f, 0.f};

    int cur = 0;
    for (int tile = 0; tile < NT; ++tile) {
        const int nxt2 = tile + 2;
        const int slot2 = (cur + 2 >= 3) ? cur - 1 : cur + 2;
        if (nxt2 < NT)
            stage(nxt2 << 6, slot2);

        if (tile * 64 > wrow0 + 31) {
            if (nxt2 < NT) asm volatile("s_waitcnt vmcnt(4)" ::: "memory");
            else           asm volatile("s_waitcnt vmcnt(0)" ::: "memory");
            __builtin_amdgcn_s_barrier();
            cur = (cur + 1 == 3) ? 0 : cur + 1;
            continue;
        }

        const char* ktb = smem + cur * 8192;
        const char* vtb = smem + 24576 + cur * 8192;

        // ---- swapped QK^T: K frag read once, used by both q-halves ----
        float p[2][4][4];
        __builtin_amdgcn_s_setprio(1);
        f32x4 s[2][4];
        #pragma unroll
        for (int sub = 0; sub < 4; ++sub) {
            s[0][sub] = (f32x4)0.f;
            s[1][sub] = (f32x4)0.f;
            const int krow = sub * 16 + c;
            #pragma unroll
            for (int kh = 0; kh < 2; ++kh) {
                unsigned byte = ((unsigned)krow << 7) + ((unsigned)kh << 6) + ((unsigned)g << 4);
                byte ^= (unsigned)(krow & 7) << 4;
                bf16x8 kb = *(const bf16x8*)(ktb + byte);
                #pragma unroll
                for (int qh = 0; qh < 2; ++qh)
                    s[qh][sub] = __builtin_amdgcn_mfma_f32_16x16x32_bf16(
                        kb, qa[qh][kh], s[qh][sub], 0, 0, 0);
            }
        }
        __builtin_amdgcn_s_setprio(0);

        if (tile * 64 + 79 <= wrow0) {
            #pragma unroll
            for (int qh = 0; qh < 2; ++qh)
                #pragma unroll
                for (int sub = 0; sub < 4; ++sub)
                    #pragma unroll
                    for (int r = 0; r < 4; ++r)
                        p[qh][sub][r] = fast_exp2(s[qh][sub][r] * EXPSCALE + qrel0s[qh]);
        } else {
            #pragma unroll
            for (int qh = 0; qh < 2; ++qh) {
                const int il = w * 32 + qh * 16 + c;
                const int iq = i0 + il;
                #pragma unroll
                for (int sub = 0; sub < 4; ++sub) {
                    const int jbase = tile * 64 + sub * 16 + g * 4;
                    #pragma unroll
                    for (int r = 0; r < 4; ++r) {
                        const int dj = jbase + r - iq;
                        int t17 = dj + 16;
                        t17 = t17 < 0 ? 0 : (t17 > 16 ? 16 : t17);
                        float pv = fast_exp2((s[qh][sub][r] + b2f(qrelb[il * 20 + t17])) * EXPSCALE);
                        if (dj > 0) pv = 0.f;
                        p[qh][sub][r] = pv;
                        if (dj >= -15 && dj <= 0)
                            tapssb[il * 16 + dj + 15] = (USH)f2b(pv);
                    }
                }
            }
        }

        #pragma unroll
        for (int qh = 0; qh < 2; ++qh)
            #pragma unroll
            for (int sub = 0; sub < 4; ++sub)
                l_r[qh] += (p[qh][sub][0] + p[qh][sub][1])
                         + (p[qh][sub][2] + p[qh][sub][3]);

        // ---- P -> per-wave LDS: 8 x ds_write_b64 (rows qh*16 + c) ----
        char* pw = pb + w * 4096;
        #pragma unroll
        for (int qh = 0; qh < 2; ++qh) {
            const int row = qh * 16 + c;
            #pragma unroll
            for (int sub = 0; sub < 4; ++sub) {
                const unsigned u0 = ((unsigned)(USH)f2b(p[qh][sub][1]) << 16)
                                  | (unsigned)(USH)f2b(p[qh][sub][0]);
                const unsigned u1 = ((unsigned)(USH)f2b(p[qh][sub][3]) << 16)
                                  | (unsigned)(USH)f2b(p[qh][sub][2]);
                uint2 val; val.x = u0; val.y = u1;
                unsigned byte = ((unsigned)(row * 128 + sub * 32 + g * 8))
                              ^ (((unsigned)row & 7) << 4);
                *(uint2*)(pw + byte) = val;
            }
        }

        // ---- PV: V frag read once, used by both q-halves ----
        bf16x8 pa[2][2];
        #pragma unroll
        for (int qh = 0; qh < 2; ++qh) {
            const int row = qh * 16 + c;
            #pragma unroll
            for (int jh = 0; jh < 2; ++jh) {
                unsigned byte = ((unsigned)(row * 128 + jh * 64 + g * 16))
                              ^ (((unsigned)row & 7) << 4);
                pa[qh][jh] = *(const bf16x8*)(pw + byte);
            }
        }
        __builtin_amdgcn_s_setprio(1);
        #pragma unroll
        for (int dt = 0; dt < 4; ++dt) {
            const int d = dt * 16 + c;
            #pragma unroll
            for (int jh = 0; jh < 2; ++jh) {
                unsigned byte = ((unsigned)d << 7) + ((unsigned)jh << 6) + ((unsigned)g << 4);
                byte ^= (unsigned)(d & 7) << 4;
                bf16x8 vb = *(const bf16x8*)(vtb + byte);
                #pragma unroll
                for (int qh = 0; qh < 2; ++qh)
                    acc[qh][dt] = __builtin_amdgcn_mfma_f32_16x16x32_bf16(
                        pa[qh][jh], vb, acc[qh][dt], 0, 0, 0);
            }
        }
        __builtin_amdgcn_s_setprio(0);

        if (nxt2 < NT) asm volatile("s_waitcnt vmcnt(4)" ::: "memory");
        else           asm volatile("s_waitcnt vmcnt(0)" ::: "memory");
        __builtin_amdgcn_s_barrier();
        cur = (cur + 1 == 3) ? 0 : cur + 1;
    }

    // ---- row sums ----
    #pragma unroll
    for (int qh = 0; qh < 2; ++qh) {
        float lsum = l_r[qh];
        lsum += __shfl_xor(lsum, 16);
        lsum += __shfl_xor(lsum, 32);
        if (g == 0) lsumb[w * 32 + qh * 16 + c] = lsum;
    }

    // ---- epilogue: acc[qh] rows = w*32 + qh*16 + g*4 + r ----
    #pragma unroll
    for (int qh = 0; qh < 2; ++qh) {
        #pragma unroll
        for (int r = 0; r < 4; ++r) {
            const int ilr = w * 32 + qh * 16 + g * 4 + r;
            const int iq = i0 + ilr;
            const float lsr = lsumb[ilr];
            float c0 = lsr;
            float tp[16];
            #pragma unroll
            for (int tap = 0; tap < 16; ++tap) {
                const int jg = iq + tap - 15;
                const float pv = (jg >= 0) ? b2f(tapssb[ilr * 16 + tap]) : 0.f;
                tp[tap] = pv;
                c0 -= pv;
            }
            const float invl = 1.f / lsr;
            #pragma unroll
            for (int dt = 0; dt < 4; ++dt) {
                const int d = dt * 16 + c;
                float o = acc[qh][dt][r] + c0 * b2f(lvfb[d]);
                #pragma unroll
                for (int tap = 0; tap < 16; ++tap)
                    o += tp[tap] * b2f(lvfb[(tap + 1) * 64 + d]);
                o *= invl;
                ao[((size_t)b * S_LEN + iq) * D_MODEL + h * DK + d] = (USH)f2b(o);
            }
        }
    }
}

// ---------------------------------------------------------------------------
extern "C" void kernel_launch(void* const* d_in, const int* in_sizes, int n_in,
                              void* d_out, int out_size, void* d_ws, size_t ws_size,
                              hipStream_t stream) {
    const float* x      = (const float*)d_in[0];
    const float* W_attn = (const float*)d_in[1];
    const float* b_attn = (const float*)d_in[2];
    const float* W_proj = (const float*)d_in[3];
    const float* b_proj = (const float*)d_in[4];
    const float* lut_k  = (const float*)d_in[5];
    const float* lut_v  = (const float*)d_in[6];
    float* out = (float*)d_out;

    // workspace layout (all USH)
    USH* qb    = (USH*)d_ws;            // 8M
    USH* kb    = qb + HSZ;              // 8M
    USH* vb    = kb + HSZ;              // 8M (unused)
    USH* vtg   = vb + HSZ;              // 8M (per-head transposed V, from GEMM)
    USH* aob   = vtg + HSZ;             // 8M
    USH* xb    = aob + HSZ;             // 8M
    USH* watt  = xb + HSZ;              // 3M
    USH* wproj = watt + 3145728;        // 1M

    // 0) fused prep: x->bf16, W_attn^T, W_proj^T
    prep_kernel<<<5120, 256, 0, stream>>>(x, xb, W_attn, watt, W_proj, wproj);

    // 1) QKV projection (256x128 tri-buffered, V written transposed in-kernel)
    gemm256_kernel<1><<<768, 512, 0, stream>>>(
        xb, watt, b_attn, nullptr, qb, kb, vtg, 3072, 24);

    // 2) attention (4 waves x 32 q-rows, shared K/V fragment reads)
    attn_mfma_kernel<<<1024, 256, 0, stream>>>(qb, kb, vtg, lut_k, lut_v, aob);

    // 3) output projection (256x128 tri-buffered, fp32 out)
    gemm256_kernel<0><<<256, 512, 0, stream>>>(
        aob, wproj, b_proj, out, nullptr, nullptr, nullptr, 1024, 8);
}

// Round 20
// 172.195 us; speedup vs baseline: 1.7227x; 1.1265x over previous
//
#include <hip/hip_runtime.h>
#include <hip/hip_bf16.h>
#include <math.h>

#define NH 16
#define S_LEN 1024
#define DK 64
#define D_MODEL 1024
#define HSZ 8388608          // B*NH*S*DK elements per q/k/v buffer

typedef __attribute__((ext_vector_type(8))) short bf16x8;
typedef __attribute__((ext_vector_type(4))) float f32x4;
typedef unsigned short USH;

#define EXPSCALE 0.1803368801111204f   // 0.125 * log2(e)

__device__ __forceinline__ float fast_exp2(float x) {
    return __builtin_amdgcn_exp2f(x);
}

__device__ __forceinline__ short f2b(float x) {
    union { __hip_bfloat16 h; short s; } u;
    u.h = __float2bfloat16(x);
    return u.s;
}
__device__ __forceinline__ float b2f(USH u) {
    union { unsigned i; float f; } x;
    x.i = (unsigned)u << 16;
    return x.f;
}

__device__ __forceinline__ void gload16(const void* src, void* lds) {
    __builtin_amdgcn_global_load_lds(
        (const __attribute__((address_space(1))) void*)src,
        (__attribute__((address_space(3))) void*)lds,
        16, 0, 0);
}

// ---------------------------------------------------------------------------
// Fused prep: fp32->bf16 conv of x  +  transpose-convert of W_attn, W_proj.
// ---------------------------------------------------------------------------
__global__ __launch_bounds__(256)
void prep_kernel(const float* __restrict__ x, USH* __restrict__ xb,
                 const float* __restrict__ W_attn, USH* __restrict__ watt,
                 const float* __restrict__ W_proj, USH* __restrict__ wproj) {
    const int blk = blockIdx.x;
    const int t = threadIdx.x;
    if (blk < 4096) {
        const int i = (blk * 256 + t) * 8;
        const float4 a = *(const float4*)&x[i];
        const float4 b = *(const float4*)&x[i + 4];
        ushort4 o0, o1;
        o0.x = (USH)f2b(a.x); o0.y = (USH)f2b(a.y); o0.z = (USH)f2b(a.z); o0.w = (USH)f2b(a.w);
        o1.x = (USH)f2b(b.x); o1.y = (USH)f2b(b.y); o1.z = (USH)f2b(b.z); o1.w = (USH)f2b(b.w);
        *(ushort4*)&xb[i] = o0;
        *(ushort4*)&xb[i + 4] = o1;
        return;
    }
    __shared__ USH Ts[64][65];
    const float* in;
    USH* out;
    int R, C, r0, c0;
    if (blk < 4864) {
        const int idx = blk - 4096;
        in = W_attn; out = watt; R = 1024; C = 3072;
        c0 = (idx % 48) * 64; r0 = (idx / 48) * 64;
    } else {
        const int idx = blk - 4864;
        in = W_proj; out = wproj; R = 1024; C = 1024;
        c0 = (idx % 16) * 64; r0 = (idx / 16) * 64;
    }
    const int tr = t >> 4;
    const int tc4 = (t & 15) * 4;
    #pragma unroll
    for (int ph = 0; ph < 4; ++ph) {
        const int r = ph * 16 + tr;
        const float4 v = *(const float4*)&in[(size_t)(r0 + r) * C + c0 + tc4];
        Ts[tc4 + 0][r] = (USH)f2b(v.x);
        Ts[tc4 + 1][r] = (USH)f2b(v.y);
        Ts[tc4 + 2][r] = (USH)f2b(v.z);
        Ts[tc4 + 3][r] = (USH)f2b(v.w);
    }
    __syncthreads();
    #pragma unroll
    for (int ph = 0; ph < 4; ++ph) {
        const int cc = ph * 16 + tr;
        ushort4 o;
        o.x = Ts[cc][tc4 + 0]; o.y = Ts[cc][tc4 + 1];
        o.z = Ts[cc][tc4 + 2]; o.w = Ts[cc][tc4 + 3];
        *(ushort4*)&out[(size_t)(c0 + cc) * R + r0 + tc4] = o;
    }
}

// ---------------------------------------------------------------------------
// 256x128-tile GEMM, BK=32, 512 thr (8 waves 4Mx2N), tri-buffered counted-
// vmcnt pipeline. QKV=1: V n-tiles written transposed via in-LDS transpose.
// ---------------------------------------------------------------------------
template<int QKV>
__global__ __launch_bounds__(512)
void gemm256_kernel(const USH* __restrict__ A, const USH* __restrict__ Bt,
                    const float* __restrict__ bias,
                    float* __restrict__ Cf, USH* __restrict__ Cq,
                    USH* __restrict__ Ck, USH* __restrict__ Cvt,
                    int N, int NTILN) {
    __shared__ __align__(16) USH lds[36864];   // 72 KB
    const int t = threadIdx.x;
    const int w = t >> 6, lane = t & 63, g = lane >> 4, c = lane & 15;
    const int wm = w >> 1, wn = w & 1;         // 4M x 2N waves
    const int nwg = NTILN * 32;
    const int bid = blockIdx.x;
    const int swz = (bid & 7) * (nwg >> 3) + (bid >> 3);   // nwg%8==0 bijective
    const int bn0 = (swz % NTILN) * 128;
    const int bm0 = (swz / NTILN) * 256;

    auto stage = [&](int kt, int slot) {
        const int k0 = kt * 32;
        char* base = (char*)lds + slot * 24576;
        #pragma unroll
        for (int q = 0; q < 2; ++q) {
            const int o = t * 16 + q * 8192;
            const int row = o >> 6;
            const int sc = (((o >> 4) & 3) ^ (row & 3)) * 8;
            gload16(A + (size_t)(bm0 + row) * 1024 + k0 + sc, base + o);
        }
        const int o = t * 16;
        const int row = o >> 6;
        const int sc = (((o >> 4) & 3) ^ (row & 3)) * 8;
        gload16(Bt + (size_t)(bn0 + row) * 1024 + k0 + sc, base + 16384 + o);
    };

    unsigned aoff[4], boff[4];
    #pragma unroll
    for (int i = 0; i < 4; ++i) {
        const int row = wm * 64 + i * 16 + c;
        aoff[i] = (unsigned)(row * 64) + (((unsigned)(g ^ (row & 3))) << 4);
        const int rn = wn * 64 + i * 16 + c;
        boff[i] = 16384u + (unsigned)(rn * 64) + (((unsigned)(g ^ (rn & 3))) << 4);
    }

    f32x4 acc[4][4];
    #pragma unroll
    for (int i = 0; i < 4; ++i)
        #pragma unroll
        for (int j = 0; j < 4; ++j) acc[i][j] = (f32x4)0.f;

    stage(0, 0);
    stage(1, 1);

    int cur = 0;
    for (int kt = 0; kt < 32; ++kt) {
        if (kt < 31) asm volatile("s_waitcnt vmcnt(3)" ::: "memory");
        else         asm volatile("s_waitcnt vmcnt(0)" ::: "memory");
        __builtin_amdgcn_s_barrier();

        const int slot2 = (cur + 2 >= 3) ? cur - 1 : cur + 2;
        if (kt + 2 < 32)
            stage(kt + 2, slot2);

        const char* sb = (const char*)lds + cur * 24576;
        bf16x8 af[4], bfr[4];
        #pragma unroll
        for (int i = 0; i < 4; ++i) af[i] = *(const bf16x8*)(sb + aoff[i]);
        #pragma unroll
        for (int j = 0; j < 4; ++j) bfr[j] = *(const bf16x8*)(sb + boff[j]);

        __builtin_amdgcn_s_setprio(1);
        #pragma unroll
        for (int i = 0; i < 4; ++i)
            #pragma unroll
            for (int j = 0; j < 4; ++j)
                acc[i][j] = __builtin_amdgcn_mfma_f32_16x16x32_bf16(
                    af[i], bfr[j], acc[i][j], 0, 0, 0);
        __builtin_amdgcn_s_setprio(0);

        cur = (cur + 1 == 3) ? 0 : cur + 1;
    }

    if (QKV) {
        if (bn0 < 2048) {
            #pragma unroll
            for (int i = 0; i < 4; ++i) {
                #pragma unroll
                for (int reg = 0; reg < 4; ++reg) {
                    const int m = bm0 + wm * 64 + i * 16 + g * 4 + reg;
                    const int b = m >> 10, s = m & 1023;
                    #pragma unroll
                    for (int j = 0; j < 4; ++j) {
                        const int n = bn0 + wn * 64 + j * 16 + c;
                        const float v = acc[i][j][reg] + bias[n];
                        const int which = n >> 10;
                        const int h = (n & 1023) >> 6, d = n & 63;
                        const size_t idx = (((size_t)(b * NH + h)) * S_LEN + s) * DK + d;
                        if (which == 0) Cq[idx] = (USH)f2b(v);
                        else            Ck[idx] = (USH)f2b(v);
                    }
                }
            }
        } else {
            __syncthreads();
            #pragma unroll
            for (int i = 0; i < 4; ++i) {
                const int m_local = wm * 64 + i * 16 + g * 4;
                #pragma unroll
                for (int j = 0; j < 4; ++j) {
                    const int n_local = wn * 64 + j * 16 + c;
                    const int n = bn0 + n_local;
                    ushort4 pk;
                    pk.x = (USH)f2b(acc[i][j][0] + bias[n]);
                    pk.y = (USH)f2b(acc[i][j][1] + bias[n]);
                    pk.z = (USH)f2b(acc[i][j][2] + bias[n]);
                    pk.w = (USH)f2b(acc[i][j][3] + bias[n]);
                    unsigned byte = ((unsigned)(n_local * 512 + m_local * 2))
                                  ^ (((unsigned)n_local & 7) << 4);
                    *(ushort4*)((char*)lds + byte) = pk;
                }
            }
            __syncthreads();
            const int b = bm0 >> 10, s0 = bm0 & 1023;
            const int h0 = (bn0 & 1023) >> 6;
            #pragma unroll
            for (int e = 0; e < 8; ++e) {
                const int task = e * 512 + t;
                const int n_local = task >> 5;
                const int chunk = task & 31;
                unsigned byte = ((unsigned)(n_local * 512 + chunk * 16))
                              ^ (((unsigned)n_local & 7) << 4);
                bf16x8 v = *(const bf16x8*)((char*)lds + byte);
                const int h = h0 + (n_local >> 6);
                const int d = n_local & 63;
                *(bf16x8*)&Cvt[(((size_t)(b * NH + h)) * DK + d) * S_LEN
                               + s0 + chunk * 8] = v;
            }
        }
    } else {
        #pragma unroll
        for (int i = 0; i < 4; ++i) {
            #pragma unroll
            for (int reg = 0; reg < 4; ++reg) {
                const int m = bm0 + wm * 64 + i * 16 + g * 4 + reg;
                #pragma unroll
                for (int j = 0; j < 4; ++j) {
                    const int n = bn0 + wn * 64 + j * 16 + c;
                    Cf[(size_t)m * N + n] = acc[i][j][reg] + bias[n];
                }
            }
        }
    }
}

// ---------------------------------------------------------------------------
// MFMA flash attention with SWAPPED QK^T (R17-verified best): 8 waves x 16
// q-rows, tri-buffered counted-vmcnt staging, fixed-shift softmax.
// s = mfma(K, Q) yields S^T: lane holds P[q = w*16+c][k contiguous in r] ->
// P-write is 4 x ds_write_b64. Row q lane-uniform: scalar qrel0 / row-sum.
// ---------------------------------------------------------------------------
__global__ __launch_bounds__(512, 4)
void attn_mfma_kernel(const USH* __restrict__ qb,
                      const USH* __restrict__ kbuf,
                      const USH* __restrict__ vtg,
                      const float* __restrict__ lut_k,
                      const float* __restrict__ lut_v,
                      USH* __restrict__ ao) {
    const int bid = blockIdx.x;
    const int logical = (bid & 7) * 128 + (bid >> 3);   // XCD-contiguous bh
    const int ib = 7 - (logical & 7);                   // LPT: big ib first
    const int bh = logical >> 3;
    const int b = bh >> 4, h = bh & 15;
    const int i0 = ib * 128;
    const int t = threadIdx.x;
    const int w = t >> 6;          // 0..7
    const int lane = t & 63;
    const int g = lane >> 4;
    const int c = lane & 15;

    __shared__ __align__(16) char smem[77440];
    char* pb     = smem + 49152;             // P buffers (main loop)
    char* qsb    = smem + 49152;             // phase0 alias: q [128][64] swz
    char* lutkb  = smem + 8192;              // phase0 alias of ktb1
    USH* qrelb   = (USH*)(smem + 65536);     // [128][20] bf16
    USH* lvfb    = (USH*)(smem + 70656);     // [17][64] bf16
    USH* tapssb  = (USH*)(smem + 72832);     // [128][16] bf16 p values
    float* lsumb = (float*)(smem + 76928);   // [128] row sums

    const USH* qp  = qb   + (size_t)bh * (S_LEN * DK);
    const USH* kp  = kbuf + (size_t)bh * (S_LEN * DK);
    const USH* vtp = vtg  + (size_t)bh * (S_LEN * DK);  // [d=64][s=1024]

    auto stage = [&](int j0, int slot) {
        const int o = t * 16;
        const int row = o >> 7;
        const int chunk = (o >> 4) & 7;
        const int sc = (chunk ^ (row & 7)) * 8;
        gload16(kp + (size_t)(j0 + row) * DK + sc, smem + slot * 8192 + o);
        gload16(vtp + (size_t)row * S_LEN + j0 + sc, smem + 24576 + slot * 8192 + o);
    };

    // ---- phase 0 ----
    stage(0, 0);
    for (int f = t; f < 2048; f += 512) {
        const int row = f >> 4, c4 = (f & 15) * 4;
        unsigned byte = ((unsigned)(row * 128 + c4 * 2)) ^ (((unsigned)row & 7) << 4);
        *(ushort4*)(qsb + byte) = *(const ushort4*)&qp[(size_t)(i0 + row) * DK + c4];
    }
    for (int e = t; e < 32 * 64; e += 512) {
        const int row = e >> 6, d = e & 63;
        const USH v = (row < 17) ? (USH)f2b(lut_k[row * 64 + d]) : (USH)0;
        unsigned byte = ((unsigned)(row * 128 + d * 2)) ^ (((unsigned)row & 7) << 4);
        *(USH*)(lutkb + byte) = v;
    }
    for (int e = t; e < 17 * 64; e += 512)
        lvfb[e] = (USH)f2b(lut_v[e]);
    __syncthreads();

    bf16x8 qa[2];
    {
        const int row = w * 16 + c;
        #pragma unroll
        for (int kh = 0; kh < 2; ++kh) {
            unsigned byte = ((unsigned)(row * 128 + kh * 64 + g * 16))
                          ^ (((unsigned)row & 7) << 4);
            qa[kh] = *(const bf16x8*)(qsb + byte);
        }
    }

    {
        f32x4 qr[2];
        qr[0] = (f32x4)0.f; qr[1] = (f32x4)0.f;
        #pragma unroll
        for (int sub2 = 0; sub2 < 2; ++sub2) {
            const int tap = sub2 * 16 + c;
            #pragma unroll
            for (int kh = 0; kh < 2; ++kh) {
                unsigned byte = ((unsigned)(tap * 128 + kh * 64 + g * 16))
                              ^ (((unsigned)tap & 7) << 4);
                bf16x8 lb = *(const bf16x8*)(lutkb + byte);
                qr[sub2] = __builtin_amdgcn_mfma_f32_16x16x32_bf16(
                    qa[kh], lb, qr[sub2], 0, 0, 0);
            }
        }
        #pragma unroll
        for (int sub2 = 0; sub2 < 2; ++sub2) {
            const int tap = sub2 * 16 + c;
            if (tap < 17) {
                #pragma unroll
                for (int r = 0; r < 4; ++r)
                    qrelb[(w * 16 + g * 4 + r) * 20 + tap] = (USH)f2b(qr[sub2][r]);
            }
        }
    }
    __syncthreads();   // qsb/lutkb reads done; overlay safe; qrelb visible

    const int il = w * 16 + c;         // this lane's q-row (swapped layout)
    const float qrel0s = b2f(qrelb[il * 20]) * EXPSCALE;

    const int NT = 2 * ib + 2;
    if (1 < NT) stage(64, 1);

    f32x4 acc[4];
    #pragma unroll
    for (int dt = 0; dt < 4; ++dt) acc[dt] = (f32x4)0.f;
    float l_r = 0.f;                   // per-lane partial sum for row il

    const int wrow0 = i0 + w * 16;
    int cur = 0;
    for (int tile = 0; tile < NT; ++tile) {
        const int nxt2 = tile + 2;
        const int slot2 = (cur + 2 >= 3) ? cur - 1 : cur + 2;
        if (nxt2 < NT)
            stage(nxt2 << 6, slot2);

        if (tile * 64 > wrow0 + 15) {
            if (nxt2 < NT) asm volatile("s_waitcnt vmcnt(2)" ::: "memory");
            else           asm volatile("s_waitcnt vmcnt(0)" ::: "memory");
            __builtin_amdgcn_s_barrier();
            cur = (cur + 1 == 3) ? 0 : cur + 1;
            continue;
        }

        const char* ktb = smem + cur * 8192;
        const char* vtb = smem + 24576 + cur * 8192;

        // ---- swapped QK^T: s[sub] = K_sub x Q^T  (S^T fragments) ----
        float p[4][4];
        __builtin_amdgcn_s_setprio(1);
        f32x4 s[4];
        #pragma unroll
        for (int sub = 0; sub < 4; ++sub) {
            s[sub] = (f32x4)0.f;
            const int krow = sub * 16 + c;
            #pragma unroll
            for (int kh = 0; kh < 2; ++kh) {
                unsigned byte = ((unsigned)krow << 7) + ((unsigned)kh << 6) + ((unsigned)g << 4);
                byte ^= (unsigned)(krow & 7) << 4;
                bf16x8 kb = *(const bf16x8*)(ktb + byte);
                s[sub] = __builtin_amdgcn_mfma_f32_16x16x32_bf16(kb, qa[kh], s[sub], 0, 0, 0);
            }
        }
        __builtin_amdgcn_s_setprio(0);

        if (tile * 64 + 79 <= wrow0) {
            #pragma unroll
            for (int sub = 0; sub < 4; ++sub)
                #pragma unroll
                for (int r = 0; r < 4; ++r)
                    p[sub][r] = fast_exp2(s[sub][r] * EXPSCALE + qrel0s);
        } else {
            #pragma unroll
            for (int sub = 0; sub < 4; ++sub) {
                const int jbase = tile * 64 + sub * 16 + g * 4;
                #pragma unroll
                for (int r = 0; r < 4; ++r) {
                    const int dj = jbase + r - (i0 + il);
                    int t17 = dj + 16;
                    t17 = t17 < 0 ? 0 : (t17 > 16 ? 16 : t17);
                    float pv = fast_exp2((s[sub][r] + b2f(qrelb[il * 20 + t17])) * EXPSCALE);
                    if (dj > 0) pv = 0.f;
                    p[sub][r] = pv;
                    if (dj >= -15 && dj <= 0)
                        tapssb[il * 16 + dj + 15] = (USH)f2b(pv);
                }
            }
        }

        #pragma unroll
        for (int sub = 0; sub < 4; ++sub)
            l_r += (p[sub][0] + p[sub][1]) + (p[sub][2] + p[sub][3]);

        // ---- P -> per-wave LDS: 4 x ds_write_b64, row = il (q) ----
        char* pw = pb + w * 2048;
        #pragma unroll
        for (int sub = 0; sub < 4; ++sub) {
            const unsigned u0 = ((unsigned)(USH)f2b(p[sub][1]) << 16)
                              | (unsigned)(USH)f2b(p[sub][0]);
            const unsigned u1 = ((unsigned)(USH)f2b(p[sub][3]) << 16)
                              | (unsigned)(USH)f2b(p[sub][2]);
            uint2 val; val.x = u0; val.y = u1;
            unsigned byte = ((unsigned)(c * 128 + sub * 32 + g * 8))
                          ^ (((unsigned)c & 7) << 4);
            *(uint2*)(pw + byte) = val;
        }

        // ---- PV (A=P from LDS, B=V^T) ----
        bf16x8 pa[2];
        #pragma unroll
        for (int jh = 0; jh < 2; ++jh) {
            unsigned byte = ((unsigned)c << 7) + ((unsigned)jh << 6) + ((unsigned)g << 4);
            byte ^= (unsigned)(c & 7) << 4;
            pa[jh] = *(const bf16x8*)(pw + byte);
        }
        __builtin_amdgcn_s_setprio(1);
        #pragma unroll
        for (int dt = 0; dt < 4; ++dt) {
            const int d = dt * 16 + c;
            #pragma unroll
            for (int jh = 0; jh < 2; ++jh) {
                unsigned byte = ((unsigned)d << 7) + ((unsigned)jh << 6) + ((unsigned)g << 4);
                byte ^= (unsigned)(d & 7) << 4;
                bf16x8 vb = *(const bf16x8*)(vtb + byte);
                acc[dt] = __builtin_amdgcn_mfma_f32_16x16x32_bf16(pa[jh], vb, acc[dt], 0, 0, 0);
            }
        }
        __builtin_amdgcn_s_setprio(0);

        if (nxt2 < NT) asm volatile("s_waitcnt vmcnt(2)" ::: "memory");
        else           asm volatile("s_waitcnt vmcnt(0)" ::: "memory");
        __builtin_amdgcn_s_barrier();
        cur = (cur + 1 == 3) ? 0 : cur + 1;
    }

    // ---- reduce row sum for row il (lanes c, c+16, c+32, c+48) ----
    float lsum = l_r;
    lsum += __shfl_xor(lsum, 16);
    lsum += __shfl_xor(lsum, 32);
    if (g == 0) lsumb[il] = lsum;      // same-wave DS order covers the read

    // ---- epilogue (acc rows = w*16 + g*4 + r, cols = dt*16 + c) ----
    const int rbase = w * 16 + g * 4;
    #pragma unroll
    for (int r = 0; r < 4; ++r) {
        const int ilr = rbase + r;
        const float lsr = lsumb[w * 16 + g * 4 + r];
        float c0 = lsr;
        float tp[16];
        #pragma unroll
        for (int tap = 0; tap < 16; ++tap) {
            const int jg = i0 + ilr + tap - 15;
            const float pv = (jg >= 0) ? b2f(tapssb[ilr * 16 + tap]) : 0.f;
            tp[tap] = pv;
            c0 -= pv;
        }
        const float invl = 1.f / lsr;
        #pragma unroll
        for (int dt = 0; dt < 4; ++dt) {
            const int d = dt * 16 + c;
            float o = acc[dt][r] + c0 * b2f(lvfb[d]);
            #pragma unroll
            for (int tap = 0; tap < 16; ++tap)
                o += tp[tap] * b2f(lvfb[(tap + 1) * 64 + d]);
            o *= invl;
            ao[((size_t)b * S_LEN + (i0 + ilr)) * D_MODEL + h * DK + d] = (USH)f2b(o);
        }
    }
}

// ---------------------------------------------------------------------------
extern "C" void kernel_launch(void* const* d_in, const int* in_sizes, int n_in,
                              void* d_out, int out_size, void* d_ws, size_t ws_size,
                              hipStream_t stream) {
    const float* x      = (const float*)d_in[0];
    const float* W_attn = (const float*)d_in[1];
    const float* b_attn = (const float*)d_in[2];
    const float* W_proj = (const float*)d_in[3];
    const float* b_proj = (const float*)d_in[4];
    const float* lut_k  = (const float*)d_in[5];
    const float* lut_v  = (const float*)d_in[6];
    float* out = (float*)d_out;

    // workspace layout (all USH)
    USH* qb    = (USH*)d_ws;            // 8M
    USH* kb    = qb + HSZ;              // 8M
    USH* vb    = kb + HSZ;              // 8M (unused)
    USH* vtg   = vb + HSZ;              // 8M (per-head transposed V, from GEMM)
    USH* aob   = vtg + HSZ;             // 8M
    USH* xb    = aob + HSZ;             // 8M
    USH* watt  = xb + HSZ;              // 3M
    USH* wproj = watt + 3145728;        // 1M

    // 0) fused prep: x->bf16, W_attn^T, W_proj^T
    prep_kernel<<<5120, 256, 0, stream>>>(x, xb, W_attn, watt, W_proj, wproj);

    // 1) QKV projection (256x128 tri-buffered, V written transposed in-kernel)
    gemm256_kernel<1><<<768, 512, 0, stream>>>(
        xb, watt, b_attn, nullptr, qb, kb, vtg, 3072, 24);

    // 2) attention (swapped-QK^T, 8 waves x 16 q-rows — R17 best)
    attn_mfma_kernel<<<1024, 512, 0, stream>>>(qb, kb, vtg, lut_k, lut_v, aob);

    // 3) output projection (256x128 tri-buffered, fp32 out)
    gemm256_kernel<0><<<256, 512, 0, stream>>>(
        aob, wproj, b_proj, out, nullptr, nullptr, nullptr, 1024, 8);
}